// Round 5
// baseline (207.786 us; speedup 1.0000x reference)
//
#include <hip/hip_runtime.h>
#include <hip/hip_bf16.h>

// InputProjection: shared LayerNorm + Q/K/V projections.
// DTYPES (R1+R4 lessons): inputs FP32, OUTPUT IS FP32 (reference output dtype).
// Internal compute: bf16 MFMA with fp32 accumulate (within 7.8e-2 tolerance).
//
// Stage 1: LayerNorm fp32 -> xn bf16 in d_ws[0..64MiB).
// Stage 1b: Wq/Wk/Wv fp32 -> bf16 in d_ws[64MiB..67MiB).
// Stage 2: GEMM xn[32768x1024] @ W^T, m97 structure: 128x128 tile, BK=64,
//          global_load_lds(16B), mfma_f32_16x16x32_bf16, fp32 bias+scatter.

#define HIDDEN 1024
#define NTOK   32768
#define BM     128
#define BN     128
#define BK     64

typedef __bf16 bf16x8 __attribute__((ext_vector_type(8)));
typedef float  f32x4  __attribute__((ext_vector_type(4)));

#define GLOBAL_AS(p) ((const __attribute__((address_space(1))) void*)(p))
#define LDS_AS(p)    ((__attribute__((address_space(3))) void*)(p))

__device__ __forceinline__ unsigned short f2bf(float f) {
  union { float f; unsigned int i; } x; x.f = f;
  unsigned int r = x.i + 0x7FFFu + ((x.i >> 16) & 1u);   // RNE
  return (unsigned short)(r >> 16);
}

// ---------------- Stage 1: LayerNorm (fp32 in, bf16 out) ----------------
__global__ __launch_bounds__(256) void ln_kernel(
    const float* __restrict__ x,
    const float* __restrict__ gamma,
    const float* __restrict__ beta,
    unsigned short* __restrict__ xn) {
  const int row = blockIdx.x;
  const int t   = threadIdx.x;
  const size_t base = (size_t)row * HIDDEN;

  const float4 v = ((const float4*)(x + base))[t];
  float s  = v.x + v.y + v.z + v.w;
  float s2 = v.x*v.x + v.y*v.y + v.z*v.z + v.w*v.w;
#pragma unroll
  for (int off = 32; off >= 1; off >>= 1) {
    s  += __shfl_xor(s,  off);
    s2 += __shfl_xor(s2, off);
  }
  __shared__ float red[8];
  const int w = t >> 6;
  if ((t & 63) == 0) { red[w] = s; red[4 + w] = s2; }
  __syncthreads();
  s  = red[0] + red[1] + red[2] + red[3];
  s2 = red[4] + red[5] + red[6] + red[7];
  const float mu   = s * (1.0f / HIDDEN);
  const float rstd = rsqrtf(s2 * (1.0f / HIDDEN) - mu * mu + 1e-5f);

  const float4 g  = ((const float4*)gamma)[t];
  const float4 bb = ((const float4*)beta)[t];
  ushort4 o;
  o.x = f2bf((v.x - mu) * rstd * g.x + bb.x);
  o.y = f2bf((v.y - mu) * rstd * g.y + bb.y);
  o.z = f2bf((v.z - mu) * rstd * g.z + bb.z);
  o.w = f2bf((v.w - mu) * rstd * g.w + bb.w);
  ((ushort4*)(xn + base))[t] = o;
}

// ---------------- Stage 1b: weight fp32 -> bf16 ----------------
__global__ __launch_bounds__(256) void cvt_kernel(
    const float* __restrict__ src, unsigned short* __restrict__ dst) {
  const int i = blockIdx.x * 256 + threadIdx.x;
  const float4 v = ((const float4*)src)[i];
  ushort4 o;
  o.x = f2bf(v.x); o.y = f2bf(v.y); o.z = f2bf(v.z); o.w = f2bf(v.w);
  ((ushort4*)dst)[i] = o;
}

// ---------------- Stage 2: QKV GEMM + bias + scatter (fp32 out) ----------------
// grid = (12, 256): x = N-tile (0..7 q, 8..9 k, 10..11 v), y = M-tile.
__global__ __launch_bounds__(256) void qkv_gemm(
    const unsigned short* __restrict__ xn,
    const unsigned short* __restrict__ wq,
    const unsigned short* __restrict__ wk,
    const unsigned short* __restrict__ wv,
    const float* __restrict__ bq,
    const float* __restrict__ bk,
    const float* __restrict__ bv,
    float* __restrict__ out) {
  __shared__ unsigned short Alds[BM * BK];   // [128][64] bf16, linear (gload_lds order)
  __shared__ unsigned short Blds[BN * BK];

  const int tn   = blockIdx.x;
  const int brow = blockIdx.y * BM;

  const unsigned short* wptr; const float* biasptr;
  int segcol; size_t obase; int hg;
  if (tn < 8)       { wptr = wq; biasptr = bq; segcol = tn * BN;        obase = 0u;        hg = 16; }
  else if (tn < 10) { wptr = wk; biasptr = bk; segcol = (tn - 8) * BN;  obase = 33554432u; hg = 4;  }
  else              { wptr = wv; biasptr = bv; segcol = (tn - 10) * BN; obase = 41943040u; hg = 4;  }

  const int t = threadIdx.x;
  const int w = t >> 6, lane = t & 63;
  const int wr = (w >> 1) * 64;
  const int wc = (w & 1)  * 64;

  f32x4 acc[4][4];
#pragma unroll
  for (int m = 0; m < 4; ++m)
#pragma unroll
    for (int n = 0; n < 4; ++n) acc[m][n] = (f32x4){0.f, 0.f, 0.f, 0.f};

  // staging: thread t covers tile elems (i*256+t)*8 .. +7 -> row = i*32 + t/8, col = (t&7)*8
  const int srow = t >> 3;
  const int scol = (t & 7) * 8;
  const unsigned short* aSrc = xn   + (size_t)(brow   + srow) * HIDDEN + scol;
  const unsigned short* bSrc = wptr + (size_t)(segcol + srow) * HIDDEN + scol;
  const int ldsWave = (w << 6) * 8;   // wave-uniform LDS base; HW adds lane*16B

  for (int kt = 0; kt < HIDDEN; kt += BK) {
#pragma unroll
    for (int i = 0; i < 4; ++i) {
      __builtin_amdgcn_global_load_lds(GLOBAL_AS(aSrc + (size_t)i * 32 * HIDDEN + kt),
                                       LDS_AS(Alds + i * 2048 + ldsWave), 16, 0, 0);
      __builtin_amdgcn_global_load_lds(GLOBAL_AS(bSrc + (size_t)i * 32 * HIDDEN + kt),
                                       LDS_AS(Blds + i * 2048 + ldsWave), 16, 0, 0);
    }
    __syncthreads();

    bf16x8 af[2][4], bfr[2][4];
#pragma unroll
    for (int kk = 0; kk < 2; ++kk) {
#pragma unroll
      for (int m = 0; m < 4; ++m)
        af[kk][m]  = *(const bf16x8*)(Alds + (wr + m * 16 + (lane & 15)) * BK + kk * 32 + (lane >> 4) * 8);
#pragma unroll
      for (int n = 0; n < 4; ++n)
        bfr[kk][n] = *(const bf16x8*)(Blds + (wc + n * 16 + (lane & 15)) * BK + kk * 32 + (lane >> 4) * 8);
    }
#pragma unroll
    for (int m = 0; m < 4; ++m)
#pragma unroll
      for (int n = 0; n < 4; ++n) {
        acc[m][n] = __builtin_amdgcn_mfma_f32_16x16x32_bf16(af[0][m], bfr[0][n], acc[m][n], 0, 0, 0);
        acc[m][n] = __builtin_amdgcn_mfma_f32_16x16x32_bf16(af[1][m], bfr[1][n], acc[m][n], 0, 0, 0);
      }
    __syncthreads();
  }

  // epilogue: C/D layout row=(lane>>4)*4+j, col=lane&15 (HW-probe-confirmed R4)
  const int col_l = lane & 15;
  const int row_l = (lane >> 4) * 4;
#pragma unroll
  for (int n = 0; n < 4; ++n) {
    const int ncol = segcol + wc + n * 16 + col_l;
    const float bias = biasptr[ncol];
    const int g = ncol >> 6;
    const int d = ncol & 63;
#pragma unroll
    for (int m = 0; m < 4; ++m) {
#pragma unroll
      for (int j = 0; j < 4; ++j) {
        const int token = brow + wr + m * 16 + row_l + j;
        const int b = token >> 12, s = token & 4095;
        const size_t off = obase + (size_t)(b * hg + g) * 262144u + (size_t)s * 64u + d;
        out[off] = acc[m][n][j] + bias;   // FP32 store — d_out is float*
      }
    }
  }
}

extern "C" void kernel_launch(void* const* d_in, const int* in_sizes, int n_in,
                              void* d_out, int out_size, void* d_ws, size_t ws_size,
                              hipStream_t stream) {
  const float* x  = (const float*)d_in[0];
  const float* wq = (const float*)d_in[1];
  const float* wk = (const float*)d_in[2];
  const float* wv = (const float*)d_in[3];
  const float* bq = (const float*)d_in[4];
  const float* bk = (const float*)d_in[5];
  const float* bv = (const float*)d_in[6];
  const float* g  = (const float*)d_in[7];
  const float* be = (const float*)d_in[8];
  float* out = (float*)d_out;

  unsigned short* xn  = (unsigned short*)d_ws;                          // 64 MiB
  unsigned short* wqb = (unsigned short*)((char*)d_ws + (64u << 20));   // 2 MiB
  unsigned short* wkb = wqb + 1024 * 1024;                              // 512 KiB
  unsigned short* wvb = wkb + 256 * 1024;                               // 512 KiB

  ln_kernel<<<NTOK, 256, 0, stream>>>(x, g, be, xn);
  cvt_kernel<<<1024, 256, 0, stream>>>(wq, wqb);
  cvt_kernel<<<256,  256, 0, stream>>>(wk, wkb);
  cvt_kernel<<<256,  256, 0, stream>>>(wv, wvb);
  dim3 grid(12, 256);
  qkv_gemm<<<grid, 256, 0, stream>>>(xn, wqb, wkb, wvb, bq, bk, bv, out);
}

// Round 6
// 198.935 us; speedup vs baseline: 1.0445x; 1.0445x over previous
//
#include <hip/hip_runtime.h>
#include <hip/hip_bf16.h>

// InputProjection: shared LayerNorm + Q/K/V projections (fp32 in, fp32 out).
// R6: pipelined GEMM. 256x256 tile, BK=32, quad-buffered LDS (128 KiB),
// distance-3 prefetch with counted vmcnt(8) (peeled 4/0 tail), ONE raw
// s_barrier per K-step, T2 swizzle (col ^= ((row>>1)&3)<<3) applied on the
// pre-swizzled global_load_lds source AND the ds_read side, XCD-aware block
// swizzle, s_setprio around the 32-MFMA cluster.

#define HIDDEN 1024
#define NTOK   32768

typedef __bf16 bf16x8 __attribute__((ext_vector_type(8)));
typedef float  f32x4  __attribute__((ext_vector_type(4)));

#define GLOBAL_AS(p) ((const __attribute__((address_space(1))) void*)(p))
#define LDS_AS(p)    ((__attribute__((address_space(3))) void*)(p))

__device__ __forceinline__ unsigned short f2bf(float f) {
  union { float f; unsigned int i; } x; x.f = f;
  unsigned int r = x.i + 0x7FFFu + ((x.i >> 16) & 1u);   // RNE
  return (unsigned short)(r >> 16);
}

// ---------------- Stage 1: LayerNorm (fp32 in, bf16 out) ----------------
__global__ __launch_bounds__(256) void ln_kernel(
    const float* __restrict__ x,
    const float* __restrict__ gamma,
    const float* __restrict__ beta,
    unsigned short* __restrict__ xn) {
  const int row = blockIdx.x;
  const int t   = threadIdx.x;
  const size_t base = (size_t)row * HIDDEN;

  const float4 v = ((const float4*)(x + base))[t];
  float s  = v.x + v.y + v.z + v.w;
  float s2 = v.x*v.x + v.y*v.y + v.z*v.z + v.w*v.w;
#pragma unroll
  for (int off = 32; off >= 1; off >>= 1) {
    s  += __shfl_xor(s,  off);
    s2 += __shfl_xor(s2, off);
  }
  __shared__ float red[8];
  const int w = t >> 6;
  if ((t & 63) == 0) { red[w] = s; red[4 + w] = s2; }
  __syncthreads();
  s  = red[0] + red[1] + red[2] + red[3];
  s2 = red[4] + red[5] + red[6] + red[7];
  const float mu   = s * (1.0f / HIDDEN);
  const float rstd = rsqrtf(s2 * (1.0f / HIDDEN) - mu * mu + 1e-5f);

  const float4 g  = ((const float4*)gamma)[t];
  const float4 bb = ((const float4*)beta)[t];
  ushort4 o;
  o.x = f2bf((v.x - mu) * rstd * g.x + bb.x);
  o.y = f2bf((v.y - mu) * rstd * g.y + bb.y);
  o.z = f2bf((v.z - mu) * rstd * g.z + bb.z);
  o.w = f2bf((v.w - mu) * rstd * g.w + bb.w);
  ((ushort4*)(xn + base))[t] = o;
}

// ---------------- Stage 1b: weight fp32 -> bf16 ----------------
__global__ __launch_bounds__(256) void cvt_kernel(
    const float* __restrict__ src, unsigned short* __restrict__ dst) {
  const int i = blockIdx.x * 256 + threadIdx.x;
  const float4 v = ((const float4*)src)[i];
  ushort4 o;
  o.x = f2bf(v.x); o.y = f2bf(v.y); o.z = f2bf(v.z); o.w = f2bf(v.w);
  ((ushort4*)dst)[i] = o;
}

// ---------------- Stage 2: pipelined QKV GEMM ----------------
// 768 blocks (128 M-tiles x 6 N-tiles), 512 threads (8 waves, 2Mx4N).
// Per wave: 128x64 output = 8x4 frags of 16x16. K=1024 in 32 steps of 32.
__global__ __launch_bounds__(512, 2) void qkv_gemm(
    const unsigned short* __restrict__ xn,
    const unsigned short* __restrict__ wq,
    const unsigned short* __restrict__ wk,
    const unsigned short* __restrict__ wv,
    const float* __restrict__ bq,
    const float* __restrict__ bk,
    const float* __restrict__ bv,
    float* __restrict__ out) {
  // 4 buffers x [256 rows][32 k] bf16 = 4 x 16 KiB per operand
  __shared__ unsigned short Al[4 * 8192];
  __shared__ unsigned short Bl[4 * 8192];

  // XCD-aware bijective swizzle (768 % 8 == 0)
  const int bid = blockIdx.x;
  const int swz = (bid & 7) * 96 + (bid >> 3);
  const int mt  = swz / 6;
  const int nt  = swz % 6;
  const int brow = mt * 256;

  const unsigned short* wbase; const float* biasptr;
  int segcol; size_t obase; int hg;
  if (nt < 4)       { wbase = wq + (size_t)nt * 256 * HIDDEN; biasptr = bq; segcol = nt * 256; obase = 0u;        hg = 16; }
  else if (nt == 4) { wbase = wk;                             biasptr = bk; segcol = 0;        obase = 33554432u; hg = 4;  }
  else              { wbase = wv;                             biasptr = bv; segcol = 0;        obase = 41943040u; hg = 4;  }

  const int t = threadIdx.x;
  const int w = t >> 6, lane = t & 63;
  const int wm = w >> 2, wn = w & 3;           // wave tile: rows wm*128, cols wn*64
  const int l15 = lane & 15, hi = lane >> 4;

  // ---- staging addresses (issue i covers rows i*128..i*128+127) ----
  // e = i*512 + t; row = e>>2; src col = ((e&3)*8) ^ swizzle(row)
  const int r0 = t >> 2,        c0 = ((t & 3) * 8) ^ (((r0 >> 1) & 3) << 3);
  const int r1 = (512 + t) >> 2, c1 = ((t & 3) * 8) ^ (((r1 >> 1) & 3) << 3);
  const unsigned short* aS0 = xn    + (size_t)(brow + r0) * HIDDEN + c0;
  const unsigned short* aS1 = xn    + (size_t)(brow + r1) * HIDDEN + c1;
  const unsigned short* bS0 = wbase + (size_t)r0 * HIDDEN + c0;
  const unsigned short* bS1 = wbase + (size_t)r1 * HIDDEN + c1;
  const int ldsW = w * 512;   // wave-uniform elems; HW adds lane*16B

  // ---- fragment read offsets (elems), swizzled ----
  const int sz   = ((l15 >> 1) & 3) << 3;
  const int aOff0 = (wm * 128 + l15) * 32 + ((hi * 8) ^ sz);
  const int bOff0 = (wn * 64  + l15) * 32 + ((hi * 8) ^ sz);

  f32x4 acc[8][4];
#pragma unroll
  for (int m = 0; m < 8; ++m)
#pragma unroll
    for (int n = 0; n < 4; ++n) acc[m][n] = (f32x4){0.f, 0.f, 0.f, 0.f};

  auto stage = [&](int j) {
    const int bb = (j & 3) * 8192;
    const int kk = j << 5;
    __builtin_amdgcn_global_load_lds(GLOBAL_AS(aS0 + kk), LDS_AS(Al + bb + ldsW),        16, 0, 0);
    __builtin_amdgcn_global_load_lds(GLOBAL_AS(aS1 + kk), LDS_AS(Al + bb + 4096 + ldsW), 16, 0, 0);
    __builtin_amdgcn_global_load_lds(GLOBAL_AS(bS0 + kk), LDS_AS(Bl + bb + ldsW),        16, 0, 0);
    __builtin_amdgcn_global_load_lds(GLOBAL_AS(bS1 + kk), LDS_AS(Bl + bb + 4096 + ldsW), 16, 0, 0);
  };

  auto compute = [&](int j) {
    const unsigned short* Ab = Al + (j & 3) * 8192;
    const unsigned short* Bb = Bl + (j & 3) * 8192;
    bf16x8 bfr[4];
#pragma unroll
    for (int n = 0; n < 4; ++n) bfr[n] = *(const bf16x8*)(Bb + bOff0 + n * 512);
    bf16x8 af[8];
#pragma unroll
    for (int m = 0; m < 8; ++m) af[m] = *(const bf16x8*)(Ab + aOff0 + m * 512);
    __builtin_amdgcn_s_setprio(1);
#pragma unroll
    for (int m = 0; m < 8; ++m)
#pragma unroll
      for (int n = 0; n < 4; ++n)
        acc[m][n] = __builtin_amdgcn_mfma_f32_16x16x32_bf16(af[m], bfr[n], acc[m][n], 0, 0, 0);
    __builtin_amdgcn_s_setprio(0);
  };

#define KSTEP(J, VMN, PF) do {                                        \
    asm volatile("s_waitcnt vmcnt(" #VMN ")" ::: "memory");           \
    __builtin_amdgcn_s_barrier();                                     \
    __builtin_amdgcn_sched_barrier(0);                                \
    if (PF) stage((J) + 3);                                           \
    compute(J);                                                       \
  } while (0)

  // prologue: 3 K-steps in flight (12 loads)
  stage(0); stage(1); stage(2);
  for (int j = 0; j < 29; ++j) { KSTEP(j, 8, true); }
  KSTEP(29, 8, false);
  KSTEP(30, 4, false);
  KSTEP(31, 0, false);
#undef KSTEP

  // ---- epilogue: bias + scatter (fp32). C/D: row=(lane>>4)*4+j, col=lane&15 ----
  const int col_l = l15;
  const int row_l = hi * 4;
#pragma unroll
  for (int n = 0; n < 4; ++n) {
    const int ncolseg = segcol + wn * 64 + n * 16 + col_l;
    const float bias = biasptr[ncolseg];
    const int g = ncolseg >> 6;
    const int d = ncolseg & 63;
#pragma unroll
    for (int m = 0; m < 8; ++m) {
#pragma unroll
      for (int j = 0; j < 4; ++j) {
        const int token = brow + wm * 128 + m * 16 + row_l + j;
        const int b = token >> 12, s = token & 4095;
        const size_t off = obase + (size_t)(b * hg + g) * 262144u + (size_t)s * 64u + d;
        out[off] = acc[m][n][j] + bias;
      }
    }
  }
}

extern "C" void kernel_launch(void* const* d_in, const int* in_sizes, int n_in,
                              void* d_out, int out_size, void* d_ws, size_t ws_size,
                              hipStream_t stream) {
  const float* x  = (const float*)d_in[0];
  const float* wq = (const float*)d_in[1];
  const float* wk = (const float*)d_in[2];
  const float* wv = (const float*)d_in[3];
  const float* bq = (const float*)d_in[4];
  const float* bk = (const float*)d_in[5];
  const float* bv = (const float*)d_in[6];
  const float* g  = (const float*)d_in[7];
  const float* be = (const float*)d_in[8];
  float* out = (float*)d_out;

  unsigned short* xn  = (unsigned short*)d_ws;                          // 64 MiB
  unsigned short* wqb = (unsigned short*)((char*)d_ws + (64u << 20));   // 2 MiB
  unsigned short* wkb = wqb + 1024 * 1024;                              // 512 KiB
  unsigned short* wvb = wkb + 256 * 1024;                               // 512 KiB

  ln_kernel<<<NTOK, 256, 0, stream>>>(x, g, be, xn);
  cvt_kernel<<<1024, 256, 0, stream>>>(wq, wqb);
  cvt_kernel<<<256,  256, 0, stream>>>(wk, wkb);
  cvt_kernel<<<256,  256, 0, stream>>>(wv, wvb);
  qkv_gemm<<<768, 512, 0, stream>>>(xn, wqb, wkb, wvb, bq, bk, bv, out);
}

// Round 8
// 188.141 us; speedup vs baseline: 1.1044x; 1.0574x over previous
//
#include <hip/hip_runtime.h>
#include <hip/hip_bf16.h>

// InputProjection: shared LayerNorm + Q/K/V projections (fp32 in, fp32 out).
// R8 = R7 with the vmcnt protocol fixed: region validation (vmcnt wait) now
// happens at the END of the phase BEFORE the consuming phase, followed by the
// phase-closing s_barrier — so every wave's staging is landed before any wave
// reads the region. Prologue gains VMW(10)+s_barrier. Ledger (per wave, 2
// loads/stage-macro): steady state drains to 10 at ends of P1/P3/P5/P7,
// releasing exactly the (A,B) half-pair the next even phase reads;
// tail 8/4/0.

#define HIDDEN 1024
#define NTOK   32768

typedef __bf16 bf16x8 __attribute__((ext_vector_type(8)));
typedef float  f32x4  __attribute__((ext_vector_type(4)));

#define GLOBAL_AS(p) ((const __attribute__((address_space(1))) void*)(p))
#define LDS_AS(p)    ((__attribute__((address_space(3))) void*)(p))

__device__ __forceinline__ unsigned short f2bf(float f) {
  union { float f; unsigned int i; } x; x.f = f;
  unsigned int r = x.i + 0x7FFFu + ((x.i >> 16) & 1u);   // RNE
  return (unsigned short)(r >> 16);
}

// ---------------- Stage 1: LayerNorm (fp32 in, bf16 out) ----------------
__global__ __launch_bounds__(256) void ln_kernel(
    const float* __restrict__ x,
    const float* __restrict__ gamma,
    const float* __restrict__ beta,
    unsigned short* __restrict__ xn) {
  const int row = blockIdx.x;
  const int t   = threadIdx.x;
  const size_t base = (size_t)row * HIDDEN;

  const float4 v = ((const float4*)(x + base))[t];
  float s  = v.x + v.y + v.z + v.w;
  float s2 = v.x*v.x + v.y*v.y + v.z*v.z + v.w*v.w;
#pragma unroll
  for (int off = 32; off >= 1; off >>= 1) {
    s  += __shfl_xor(s,  off);
    s2 += __shfl_xor(s2, off);
  }
  __shared__ float red[8];
  const int w = t >> 6;
  if ((t & 63) == 0) { red[w] = s; red[4 + w] = s2; }
  __syncthreads();
  s  = red[0] + red[1] + red[2] + red[3];
  s2 = red[4] + red[5] + red[6] + red[7];
  const float mu   = s * (1.0f / HIDDEN);
  const float rstd = rsqrtf(s2 * (1.0f / HIDDEN) - mu * mu + 1e-5f);

  const float4 g  = ((const float4*)gamma)[t];
  const float4 bb = ((const float4*)beta)[t];
  ushort4 o;
  o.x = f2bf((v.x - mu) * rstd * g.x + bb.x);
  o.y = f2bf((v.y - mu) * rstd * g.y + bb.y);
  o.z = f2bf((v.z - mu) * rstd * g.z + bb.z);
  o.w = f2bf((v.w - mu) * rstd * g.w + bb.w);
  ((ushort4*)(xn + base))[t] = o;
}

// ---------------- Stage 1b: weight fp32 -> bf16 ----------------
__global__ __launch_bounds__(256) void cvt_kernel(
    const float* __restrict__ src, unsigned short* __restrict__ dst) {
  const int i = blockIdx.x * 256 + threadIdx.x;
  const float4 v = ((const float4*)src)[i];
  ushort4 o;
  o.x = f2bf(v.x); o.y = f2bf(v.y); o.z = f2bf(v.z); o.w = f2bf(v.w);
  ((ushort4*)dst)[i] = o;
}

// ---------------- Stage 2: 8-phase QKV GEMM ----------------
// 768 blocks (128 M x 6 N), 512 threads (8 waves, 2M x 4N), wave tile 128x64.
__global__ __launch_bounds__(512, 2) void qkv_gemm(
    const unsigned short* __restrict__ xn,
    const unsigned short* __restrict__ wq,
    const unsigned short* __restrict__ wk,
    const unsigned short* __restrict__ wv,
    const float* __restrict__ bq,
    const float* __restrict__ bk,
    const float* __restrict__ bv,
    float* __restrict__ out) {
  // [2 buf][2 kk][256 rows][32 k] bf16 per operand = 64 KiB each
  __shared__ unsigned short Alds[32768];
  __shared__ unsigned short Blds[32768];

  // XCD-aware bijective swizzle (768 % 8 == 0)
  const int bid = blockIdx.x;
  const int swz = (bid & 7) * 96 + (bid >> 3);
  const int mt  = swz / 6;
  const int nt  = swz % 6;
  const int brow = mt * 256;

  const unsigned short* wbase; const float* biasptr;
  int segcol; size_t obase; int hg;
  if (nt < 4)       { wbase = wq + (size_t)nt * 256 * HIDDEN; biasptr = bq; segcol = nt * 256; obase = 0u;        hg = 16; }
  else if (nt == 4) { wbase = wk;                             biasptr = bk; segcol = 0;        obase = 33554432u; hg = 4;  }
  else              { wbase = wv;                             biasptr = bv; segcol = 0;        obase = 41943040u; hg = 4;  }

  const int t = threadIdx.x;
  const int w = t >> 6, lane = t & 63;
  const int wm = w >> 2, wn = w & 3;
  const int l15 = lane & 15, hi = lane >> 4;

  // stage geometry: instr pair covers rows [32w,32w+16) and [32w+16,32w+32);
  // lane: row = 32w + (lane>>2), granule = (lane&3) ^ ((lane>>2)&3)  -> LDS[row][g] = global[row][g^(row&3)]
  const int sr  = 2 * w * 16 + (lane >> 2);
  const int scg = ((lane & 3) ^ ((lane >> 2) & 3)) * 8;
  const unsigned short* aST = xn    + (size_t)(brow + sr) * HIDDEN + scg;
  const unsigned short* bST = wbase + (size_t)sr * HIDDEN + scg;
  const int ldsq = 2 * w * 512;   // wave-uniform elems; HW adds lane*16B

  // ds_read geometry: addr = buf*16384 + kk*8192 + row*32 + ((hi^(row&3))*8
  const int rdx  = (hi ^ (l15 & 3)) * 8;
  const int rowA = wm * 128 + l15;
  const int rowB = wn * 64  + l15;

  f32x4 acc[8][4];
#pragma unroll
  for (int m = 0; m < 8; ++m)
#pragma unroll
    for (int n = 0; n < 4; ++n) acc[m][n] = (f32x4){0.f, 0.f, 0.f, 0.f};
  bf16x8 a[8], b[2];

#define STA(BUF, KK, KT) do {                                                   \
    unsigned short* _d = Alds + (BUF) * 16384 + (KK) * 8192 + ldsq;             \
    const unsigned short* _s = aST + (size_t)((KT) * 64 + (KK) * 32);           \
    __builtin_amdgcn_global_load_lds(GLOBAL_AS(_s), LDS_AS(_d), 16, 0, 0);      \
    __builtin_amdgcn_global_load_lds(GLOBAL_AS(_s + 16 * HIDDEN), LDS_AS(_d + 512), 16, 0, 0); \
  } while (0)
#define STB(BUF, KK, KT) do {                                                   \
    unsigned short* _d = Blds + (BUF) * 16384 + (KK) * 8192 + ldsq;             \
    const unsigned short* _s = bST + (size_t)((KT) * 64 + (KK) * 32);           \
    __builtin_amdgcn_global_load_lds(GLOBAL_AS(_s), LDS_AS(_d), 16, 0, 0);      \
    __builtin_amdgcn_global_load_lds(GLOBAL_AS(_s + 16 * HIDDEN), LDS_AS(_d + 512), 16, 0, 0); \
  } while (0)
#define DSA(BUF, KK) do { _Pragma("unroll")                                     \
    for (int m = 0; m < 8; ++m)                                                 \
      a[m] = *(const bf16x8*)(Alds + (BUF) * 16384 + (KK) * 8192 + (rowA + m * 16) * 32 + rdx); \
  } while (0)
#define DSB(BUF, KK, NB) do { _Pragma("unroll")                                 \
    for (int n = 0; n < 2; ++n)                                                 \
      b[n] = *(const bf16x8*)(Blds + (BUF) * 16384 + (KK) * 8192 + (rowB + ((NB) + n) * 16) * 32 + rdx); \
  } while (0)
#define MM(NB) do {                                                             \
    __builtin_amdgcn_s_setprio(1);                                              \
    _Pragma("unroll") for (int m = 0; m < 8; ++m) {                             \
      acc[m][(NB)]     = __builtin_amdgcn_mfma_f32_16x16x32_bf16(a[m], b[0], acc[m][(NB)], 0, 0, 0);     \
      acc[m][(NB) + 1] = __builtin_amdgcn_mfma_f32_16x16x32_bf16(a[m], b[1], acc[m][(NB) + 1], 0, 0, 0); \
    }                                                                           \
    __builtin_amdgcn_s_setprio(0);                                              \
  } while (0)
#define BARS do { __builtin_amdgcn_s_barrier();                                 \
    asm volatile("s_waitcnt lgkmcnt(0)" ::: "memory");                          \
    __builtin_amdgcn_sched_barrier(0); } while (0)
#define ENDB do { __builtin_amdgcn_s_barrier();                                 \
    __builtin_amdgcn_sched_barrier(0); } while (0)
#define VMW(N) asm volatile("s_waitcnt vmcnt(" #N ")" ::: "memory")

  // prologue: tiles 0 (buf0: A0,B0,A1,B1) and 1 (buf1: A2,B2,A3) = 14 loads.
  // Validate tile0 kk0 (oldest 4) for everyone, then barrier.
  STA(0, 0, 0); STB(0, 0, 0); STA(0, 1, 0); STB(0, 1, 0);
  STA(1, 0, 1); STB(1, 0, 1); STA(1, 1, 1);
  VMW(10);
  __builtin_amdgcn_s_barrier();
  __builtin_amdgcn_sched_barrier(0);

  for (int i = 0; i < 7; ++i) {
    const int T = 2 * i;
    // Validation VMW sits at END of odd phases (before ENDB): drains exactly
    // the (A,B) half-pair the following even phase reads.
    /*P0*/ DSA(0, 0); DSB(0, 0, 0); STB(1, 1, T + 1); BARS; MM(0);          ENDB;
    /*P1*/ DSB(0, 0, 2);            STA(0, 0, T + 2); BARS; MM(2); VMW(10); ENDB;
    /*P2*/ DSA(0, 1); DSB(0, 1, 0); STB(0, 0, T + 2); BARS; MM(0);          ENDB;
    /*P3*/ DSB(0, 1, 2);            STA(0, 1, T + 2); BARS; MM(2); VMW(10); ENDB;
    /*P4*/ DSA(1, 0); DSB(1, 0, 0); STB(0, 1, T + 2); BARS; MM(0);          ENDB;
    /*P5*/ DSB(1, 0, 2);            STA(1, 0, T + 3); BARS; MM(2); VMW(10); ENDB;
    /*P6*/ DSA(1, 1); DSB(1, 1, 0); STB(1, 0, T + 3); BARS; MM(0);          ENDB;
    /*P7*/ DSB(1, 1, 2);            STA(1, 1, T + 3); BARS; MM(2); VMW(10); ENDB;
  }
  // tail (tiles 14,15): only P0 stages; vmcnt drains 8/4/0
  /*P0*/ DSA(0, 0); DSB(0, 0, 0); STB(1, 1, 15); BARS; MM(0);         ENDB;
  /*P1*/ DSB(0, 0, 2);                           BARS; MM(2); VMW(8); ENDB;
  /*P2*/ DSA(0, 1); DSB(0, 1, 0);                BARS; MM(0);         ENDB;
  /*P3*/ DSB(0, 1, 2);                           BARS; MM(2); VMW(4); ENDB;
  /*P4*/ DSA(1, 0); DSB(1, 0, 0);                BARS; MM(0);         ENDB;
  /*P5*/ DSB(1, 0, 2);                           BARS; MM(2); VMW(0); ENDB;
  /*P6*/ DSA(1, 1); DSB(1, 1, 0);                BARS; MM(0);         ENDB;
  /*P7*/ DSB(1, 1, 2);                           BARS; MM(2);         ENDB;

#undef STA
#undef STB
#undef DSA
#undef DSB
#undef MM
#undef BARS
#undef ENDB
#undef VMW

  // ---- epilogue: bias + scatter (fp32). C/D: row=(lane>>4)*4+j, col=lane&15 ----
  const int col_l = l15;
  const int row_l = hi * 4;
#pragma unroll
  for (int n = 0; n < 4; ++n) {
    const int ncolseg = segcol + wn * 64 + n * 16 + col_l;
    const float bias = biasptr[ncolseg];
    const int g = ncolseg >> 6;
    const int d = ncolseg & 63;
#pragma unroll
    for (int m = 0; m < 8; ++m) {
#pragma unroll
      for (int j = 0; j < 4; ++j) {
        const int token = brow + wm * 128 + m * 16 + row_l + j;
        const int b_ = token >> 12, s = token & 4095;
        const size_t off = obase + (size_t)(b_ * hg + g) * 262144u + (size_t)s * 64u + d;
        out[off] = acc[m][n][j] + bias;
      }
    }
  }
}

extern "C" void kernel_launch(void* const* d_in, const int* in_sizes, int n_in,
                              void* d_out, int out_size, void* d_ws, size_t ws_size,
                              hipStream_t stream) {
  const float* x  = (const float*)d_in[0];
  const float* wq = (const float*)d_in[1];
  const float* wk = (const float*)d_in[2];
  const float* wv = (const float*)d_in[3];
  const float* bq = (const float*)d_in[4];
  const float* bk = (const float*)d_in[5];
  const float* bv = (const float*)d_in[6];
  const float* g  = (const float*)d_in[7];
  const float* be = (const float*)d_in[8];
  float* out = (float*)d_out;

  unsigned short* xn  = (unsigned short*)d_ws;                          // 64 MiB
  unsigned short* wqb = (unsigned short*)((char*)d_ws + (64u << 20));   // 2 MiB
  unsigned short* wkb = wqb + 1024 * 1024;                              // 512 KiB
  unsigned short* wvb = wkb + 256 * 1024;                               // 512 KiB

  ln_kernel<<<NTOK, 256, 0, stream>>>(x, g, be, xn);
  cvt_kernel<<<1024, 256, 0, stream>>>(wq, wqb);
  cvt_kernel<<<256,  256, 0, stream>>>(wk, wkb);
  cvt_kernel<<<256,  256, 0, stream>>>(wv, wvb);
  qkv_gemm<<<768, 512, 0, stream>>>(xn, wqb, wkb, wvb, bq, bk, bv, out);
}

// Round 9
// 176.493 us; speedup vs baseline: 1.1773x; 1.0660x over previous
//
#include <hip/hip_runtime.h>
#include <hip/hip_bf16.h>

// InputProjection: shared LayerNorm + Q/K/V projections (fp32 in, fp32 out).
// R9 = R8 + two fixes from counters:
//  (a) LDS swizzle reverted to R6's conflict-free involution (row>>1)&3
//      (R8's (row&3) gave 4-way quarter-wave conflicts, 9.4M counted).
//  (b) Coalesced epilogue: each wave's output is a contiguous [128][64] fp32
//      block (one head) -> LDS-transpose per 16-token chunk (stride 84 f32,
//      2-way max) -> float4 stores, 1KB contiguous per instruction.

#define HIDDEN 1024
#define NTOK   32768

typedef __bf16 bf16x8 __attribute__((ext_vector_type(8)));
typedef float  f32x4  __attribute__((ext_vector_type(4)));

#define GLOBAL_AS(p) ((const __attribute__((address_space(1))) void*)(p))
#define LDS_AS(p)    ((__attribute__((address_space(3))) void*)(p))

__device__ __forceinline__ unsigned short f2bf(float f) {
  union { float f; unsigned int i; } x; x.f = f;
  unsigned int r = x.i + 0x7FFFu + ((x.i >> 16) & 1u);   // RNE
  return (unsigned short)(r >> 16);
}

// ---------------- Stage 1: LayerNorm (fp32 in, bf16 out) ----------------
__global__ __launch_bounds__(256) void ln_kernel(
    const float* __restrict__ x,
    const float* __restrict__ gamma,
    const float* __restrict__ beta,
    unsigned short* __restrict__ xn) {
  const int row = blockIdx.x;
  const int t   = threadIdx.x;
  const size_t base = (size_t)row * HIDDEN;

  const float4 v = ((const float4*)(x + base))[t];
  float s  = v.x + v.y + v.z + v.w;
  float s2 = v.x*v.x + v.y*v.y + v.z*v.z + v.w*v.w;
#pragma unroll
  for (int off = 32; off >= 1; off >>= 1) {
    s  += __shfl_xor(s,  off);
    s2 += __shfl_xor(s2, off);
  }
  __shared__ float red[8];
  const int w = t >> 6;
  if ((t & 63) == 0) { red[w] = s; red[4 + w] = s2; }
  __syncthreads();
  s  = red[0] + red[1] + red[2] + red[3];
  s2 = red[4] + red[5] + red[6] + red[7];
  const float mu   = s * (1.0f / HIDDEN);
  const float rstd = rsqrtf(s2 * (1.0f / HIDDEN) - mu * mu + 1e-5f);

  const float4 g  = ((const float4*)gamma)[t];
  const float4 bb = ((const float4*)beta)[t];
  ushort4 o;
  o.x = f2bf((v.x - mu) * rstd * g.x + bb.x);
  o.y = f2bf((v.y - mu) * rstd * g.y + bb.y);
  o.z = f2bf((v.z - mu) * rstd * g.z + bb.z);
  o.w = f2bf((v.w - mu) * rstd * g.w + bb.w);
  ((ushort4*)(xn + base))[t] = o;
}

// ---------------- Stage 1b: weight fp32 -> bf16 ----------------
__global__ __launch_bounds__(256) void cvt_kernel(
    const float* __restrict__ src, unsigned short* __restrict__ dst) {
  const int i = blockIdx.x * 256 + threadIdx.x;
  const float4 v = ((const float4*)src)[i];
  ushort4 o;
  o.x = f2bf(v.x); o.y = f2bf(v.y); o.z = f2bf(v.z); o.w = f2bf(v.w);
  ((ushort4*)dst)[i] = o;
}

// ---------------- Stage 2: 8-phase QKV GEMM ----------------
// 768 blocks (128 M x 6 N), 512 threads (8 waves, 2M x 4N), wave tile 128x64.
__global__ __launch_bounds__(512, 2) void qkv_gemm(
    const unsigned short* __restrict__ xn,
    const unsigned short* __restrict__ wq,
    const unsigned short* __restrict__ wk,
    const unsigned short* __restrict__ wv,
    const float* __restrict__ bq,
    const float* __restrict__ bk,
    const float* __restrict__ bv,
    float* __restrict__ out) {
  // [2 buf][2 kk][256 rows][32 k] bf16 per operand = 64 KiB each
  __shared__ unsigned short Alds[32768];
  __shared__ unsigned short Blds[32768];

  // XCD-aware bijective swizzle (768 % 8 == 0)
  const int bid = blockIdx.x;
  const int swz = (bid & 7) * 96 + (bid >> 3);
  const int mt  = swz / 6;
  const int nt  = swz % 6;
  const int brow = mt * 256;

  const unsigned short* wbase; const float* biasptr;
  int segcol; size_t obase; int hg;
  if (nt < 4)       { wbase = wq + (size_t)nt * 256 * HIDDEN; biasptr = bq; segcol = nt * 256; obase = 0u;        hg = 16; }
  else if (nt == 4) { wbase = wk;                             biasptr = bk; segcol = 0;        obase = 33554432u; hg = 4;  }
  else              { wbase = wv;                             biasptr = bv; segcol = 0;        obase = 41943040u; hg = 4;  }

  const int t = threadIdx.x;
  const int w = t >> 6, lane = t & 63;
  const int wm = w >> 2, wn = w & 3;
  const int l15 = lane & 15, hi = lane >> 4;

  // stage geometry: instr pair covers rows [32w,32w+16) and [32w+16,32w+32);
  // lane: row = 32w + (lane>>2), source granule = (lane&3) ^ ((row>>1)&3)
  //  -> LDS[row][g] = global[row][g ^ ((row>>1)&3)]   (R6 conflict-free form;
  //     (row+16)>>1 & 3 is unchanged, so same scg serves both instrs)
  const int sr  = 2 * w * 16 + (lane >> 2);
  const int scg = ((lane & 3) ^ ((lane >> 3) & 3)) * 8;
  const unsigned short* aST = xn    + (size_t)(brow + sr) * HIDDEN + scg;
  const unsigned short* bST = wbase + (size_t)sr * HIDDEN + scg;
  const int ldsq = 2 * w * 512;   // wave-uniform elems; HW adds lane*16B

  // ds_read: addr = buf*16384 + kk*8192 + row*32 + (hi ^ ((row>>1)&3))*8
  const int rdx  = (hi ^ ((l15 >> 1) & 3)) * 8;
  const int rowA = wm * 128 + l15;
  const int rowB = wn * 64  + l15;

  f32x4 acc[8][4];
#pragma unroll
  for (int m = 0; m < 8; ++m)
#pragma unroll
    for (int n = 0; n < 4; ++n) acc[m][n] = (f32x4){0.f, 0.f, 0.f, 0.f};
  bf16x8 a[8], b[2];

#define STA(BUF, KK, KT) do {                                                   \
    unsigned short* _d = Alds + (BUF) * 16384 + (KK) * 8192 + ldsq;             \
    const unsigned short* _s = aST + (size_t)((KT) * 64 + (KK) * 32);           \
    __builtin_amdgcn_global_load_lds(GLOBAL_AS(_s), LDS_AS(_d), 16, 0, 0);      \
    __builtin_amdgcn_global_load_lds(GLOBAL_AS(_s + 16 * HIDDEN), LDS_AS(_d + 512), 16, 0, 0); \
  } while (0)
#define STB(BUF, KK, KT) do {                                                   \
    unsigned short* _d = Blds + (BUF) * 16384 + (KK) * 8192 + ldsq;             \
    const unsigned short* _s = bST + (size_t)((KT) * 64 + (KK) * 32);           \
    __builtin_amdgcn_global_load_lds(GLOBAL_AS(_s), LDS_AS(_d), 16, 0, 0);      \
    __builtin_amdgcn_global_load_lds(GLOBAL_AS(_s + 16 * HIDDEN), LDS_AS(_d + 512), 16, 0, 0); \
  } while (0)
#define DSA(BUF, KK) do { _Pragma("unroll")                                     \
    for (int m = 0; m < 8; ++m)                                                 \
      a[m] = *(const bf16x8*)(Alds + (BUF) * 16384 + (KK) * 8192 + (rowA + m * 16) * 32 + rdx); \
  } while (0)
#define DSB(BUF, KK, NB) do { _Pragma("unroll")                                 \
    for (int n = 0; n < 2; ++n)                                                 \
      b[n] = *(const bf16x8*)(Blds + (BUF) * 16384 + (KK) * 8192 + (rowB + ((NB) + n) * 16) * 32 + rdx); \
  } while (0)
#define MM(NB) do {                                                             \
    __builtin_amdgcn_s_setprio(1);                                              \
    _Pragma("unroll") for (int m = 0; m < 8; ++m) {                             \
      acc[m][(NB)]     = __builtin_amdgcn_mfma_f32_16x16x32_bf16(a[m], b[0], acc[m][(NB)], 0, 0, 0);     \
      acc[m][(NB) + 1] = __builtin_amdgcn_mfma_f32_16x16x32_bf16(a[m], b[1], acc[m][(NB) + 1], 0, 0, 0); \
    }                                                                           \
    __builtin_amdgcn_s_setprio(0);                                              \
  } while (0)
#define BARS do { __builtin_amdgcn_s_barrier();                                 \
    asm volatile("s_waitcnt lgkmcnt(0)" ::: "memory");                          \
    __builtin_amdgcn_sched_barrier(0); } while (0)
#define ENDB do { __builtin_amdgcn_s_barrier();                                 \
    __builtin_amdgcn_sched_barrier(0); } while (0)
#define VMW(N) asm volatile("s_waitcnt vmcnt(" #N ")" ::: "memory")

  // prologue: tiles 0 (buf0) and 1 (buf1, 3 of 4 halves) = 14 loads.
  STA(0, 0, 0); STB(0, 0, 0); STA(0, 1, 0); STB(0, 1, 0);
  STA(1, 0, 1); STB(1, 0, 1); STA(1, 1, 1);
  VMW(10);
  __builtin_amdgcn_s_barrier();
  __builtin_amdgcn_sched_barrier(0);

  for (int i = 0; i < 7; ++i) {
    const int T = 2 * i;
    // Validation VMW at END of odd phases (before ENDB): drains exactly the
    // (A,B) half-pair the following even phase reads.
    /*P0*/ DSA(0, 0); DSB(0, 0, 0); STB(1, 1, T + 1); BARS; MM(0);          ENDB;
    /*P1*/ DSB(0, 0, 2);            STA(0, 0, T + 2); BARS; MM(2); VMW(10); ENDB;
    /*P2*/ DSA(0, 1); DSB(0, 1, 0); STB(0, 0, T + 2); BARS; MM(0);          ENDB;
    /*P3*/ DSB(0, 1, 2);            STA(0, 1, T + 2); BARS; MM(2); VMW(10); ENDB;
    /*P4*/ DSA(1, 0); DSB(1, 0, 0); STB(0, 1, T + 2); BARS; MM(0);          ENDB;
    /*P5*/ DSB(1, 0, 2);            STA(1, 0, T + 3); BARS; MM(2); VMW(10); ENDB;
    /*P6*/ DSA(1, 1); DSB(1, 1, 0); STB(1, 0, T + 3); BARS; MM(0);          ENDB;
    /*P7*/ DSB(1, 1, 2);            STA(1, 1, T + 3); BARS; MM(2); VMW(10); ENDB;
  }
  // tail (tiles 14,15): only P0 stages; vmcnt drains 8/4/0
  /*P0*/ DSA(0, 0); DSB(0, 0, 0); STB(1, 1, 15); BARS; MM(0);         ENDB;
  /*P1*/ DSB(0, 0, 2);                           BARS; MM(2); VMW(8); ENDB;
  /*P2*/ DSA(0, 1); DSB(0, 1, 0);                BARS; MM(0);         ENDB;
  /*P3*/ DSB(0, 1, 2);                           BARS; MM(2); VMW(4); ENDB;
  /*P4*/ DSA(1, 0); DSB(1, 0, 0);                BARS; MM(0);         ENDB;
  /*P5*/ DSB(1, 0, 2);                           BARS; MM(2); VMW(0); ENDB;
  /*P6*/ DSA(1, 1); DSB(1, 1, 0);                BARS; MM(0);         ENDB;
  /*P7*/ DSB(1, 1, 2);                           BARS; MM(2);         ENDB;

#undef STA
#undef STB
#undef DSA
#undef DSB
#undef MM
#undef BARS
#undef ENDB
#undef VMW

  // ---- epilogue: coalesced. Wave output = contiguous [128 tok][64 d] fp32
  // (one head/group). Per 16-token chunk: acc+bias -> LDS (stride 84 f32,
  // 2-way max both directions) -> float4 reads -> 1KB-contiguous stores.
  // Per-wave-disjoint LDS; DS pipe in-order per wave -> no barriers.
  float* ep = (float*)Alds;               // 8 waves x 16 x 84 f32 = 43008 B
  const int epb = w * 1344;               // 16 * 84
  const int headcol = segcol + wn * 64;
  const int gidx = headcol >> 6;
  const int tok0 = brow + wm * 128;
  const int b_ = tok0 >> 12;
  float* wout = out + obase + (size_t)(b_ * hg + gidx) * 262144u
                    + (size_t)(tok0 & 4095) * 64u;
  float biasv[4];
#pragma unroll
  for (int n = 0; n < 4; ++n) biasv[n] = biasptr[headcol + n * 16 + l15];

#pragma unroll
  for (int m = 0; m < 8; ++m) {
#pragma unroll
    for (int n = 0; n < 4; ++n)
#pragma unroll
      for (int j = 0; j < 4; ++j)
        ep[epb + (hi * 4 + j) * 84 + n * 16 + l15] = acc[m][n][j] + biasv[n];
    asm volatile("s_waitcnt lgkmcnt(0)" ::: "memory");
#pragma unroll
    for (int it = 0; it < 4; ++it) {
      const int r = it * 4 + hi;
      const float4 v = *(const float4*)(ep + epb + r * 84 + l15 * 4);
      *(float4*)(wout + (size_t)(m * 16 + r) * 64 + l15 * 4) = v;
    }
  }
}

extern "C" void kernel_launch(void* const* d_in, const int* in_sizes, int n_in,
                              void* d_out, int out_size, void* d_ws, size_t ws_size,
                              hipStream_t stream) {
  const float* x  = (const float*)d_in[0];
  const float* wq = (const float*)d_in[1];
  const float* wk = (const float*)d_in[2];
  const float* wv = (const float*)d_in[3];
  const float* bq = (const float*)d_in[4];
  const float* bk = (const float*)d_in[5];
  const float* bv = (const float*)d_in[6];
  const float* g  = (const float*)d_in[7];
  const float* be = (const float*)d_in[8];
  float* out = (float*)d_out;

  unsigned short* xn  = (unsigned short*)d_ws;                          // 64 MiB
  unsigned short* wqb = (unsigned short*)((char*)d_ws + (64u << 20));   // 2 MiB
  unsigned short* wkb = wqb + 1024 * 1024;                              // 512 KiB
  unsigned short* wvb = wkb + 256 * 1024;                               // 512 KiB

  ln_kernel<<<NTOK, 256, 0, stream>>>(x, g, be, xn);
  cvt_kernel<<<1024, 256, 0, stream>>>(wq, wqb);
  cvt_kernel<<<256,  256, 0, stream>>>(wk, wkb);
  cvt_kernel<<<256,  256, 0, stream>>>(wv, wvb);
  qkv_gemm<<<768, 512, 0, stream>>>(xn, wqb, wkb, wvb, bq, bk, bv, out);
}

// Round 11
// 171.245 us; speedup vs baseline: 1.2134x; 1.0306x over previous
//
#include <hip/hip_runtime.h>
#include <hip/hip_bf16.h>

// InputProjection: shared LayerNorm + Q/K/V projections (fp32 in, fp32 out).
// R11 = R10 + prologue race fix: s_barrier AFTER the prologue ds_reads'
// lgkmcnt(0), so no wave's P0 STB(B00,tile2) LDS-writes can land while
// another wave still reads tile-0 B00 (lgkmcnt is per-wave; B rows are
// staged/read cross-wave). All in-loop write-after-read pairs were verified
// fenced by the per-phase {lgkmcnt(0); vmcnt(N); s_barrier} protocol.

#define HIDDEN 1024
#define NTOK   32768

typedef __bf16 bf16x8 __attribute__((ext_vector_type(8)));
typedef float  f32x4  __attribute__((ext_vector_type(4)));

#define GLOBAL_AS(p) ((const __attribute__((address_space(1))) void*)(p))
#define LDS_AS(p)    ((__attribute__((address_space(3))) void*)(p))

__device__ __forceinline__ unsigned short f2bf(float f) {
  union { float f; unsigned int i; } x; x.f = f;
  unsigned int r = x.i + 0x7FFFu + ((x.i >> 16) & 1u);   // RNE
  return (unsigned short)(r >> 16);
}

// ---------------- K1: LayerNorm (fp32 in, bf16 out) + weight cvt ----------------
__global__ __launch_bounds__(256) void ln_cvt_kernel(
    const float* __restrict__ x,
    const float* __restrict__ gamma,
    const float* __restrict__ beta,
    const float* __restrict__ wq,
    const float* __restrict__ wk,
    const float* __restrict__ wv,
    unsigned short* __restrict__ xn,
    unsigned short* __restrict__ wb) {
  const int bid = blockIdx.x;
  const int t   = threadIdx.x;
  if (bid < NTOK) {
    const size_t base = (size_t)bid * HIDDEN;
    const float4 v = ((const float4*)(x + base))[t];
    float s  = v.x + v.y + v.z + v.w;
    float s2 = v.x*v.x + v.y*v.y + v.z*v.z + v.w*v.w;
#pragma unroll
    for (int off = 32; off >= 1; off >>= 1) {
      s  += __shfl_xor(s,  off);
      s2 += __shfl_xor(s2, off);
    }
    __shared__ float red[8];
    const int w = t >> 6;
    if ((t & 63) == 0) { red[w] = s; red[4 + w] = s2; }
    __syncthreads();
    s  = red[0] + red[1] + red[2] + red[3];
    s2 = red[4] + red[5] + red[6] + red[7];
    const float mu   = s * (1.0f / HIDDEN);
    const float rstd = rsqrtf(s2 * (1.0f / HIDDEN) - mu * mu + 1e-5f);
    const float4 g  = ((const float4*)gamma)[t];
    const float4 bb = ((const float4*)beta)[t];
    ushort4 o;
    o.x = f2bf((v.x - mu) * rstd * g.x + bb.x);
    o.y = f2bf((v.y - mu) * rstd * g.y + bb.y);
    o.z = f2bf((v.z - mu) * rstd * g.z + bb.z);
    o.w = f2bf((v.w - mu) * rstd * g.w + bb.w);
    ((ushort4*)(xn + base))[t] = o;
  } else {
    const int b2 = bid - NTOK;           // 0..1535; 1024 wq, 256 wk, 256 wv
    const float* src;
    int off;
    if (b2 < 1024)      { src = wq; off = b2; }
    else if (b2 < 1280) { src = wk; off = b2 - 1024; }
    else                { src = wv; off = b2 - 1280; }
    const float4 v = ((const float4*)src)[off * 256 + t];
    ushort4 o;
    o.x = f2bf(v.x); o.y = f2bf(v.y); o.z = f2bf(v.z); o.w = f2bf(v.w);
    ((ushort4*)wb)[b2 * 256 + t] = o;
  }
}

// ---------------- K2: 8-phase pipelined QKV GEMM ----------------
// 768 blocks (128 M x 6 N), 512 threads (8 waves, 2M x 4N), wave tile 128x64.
__global__ __launch_bounds__(512, 2) void qkv_gemm(
    const unsigned short* __restrict__ xn,
    const unsigned short* __restrict__ wqb,
    const float* __restrict__ bq,
    const float* __restrict__ bk,
    const float* __restrict__ bv,
    float* __restrict__ out) {
  // [2 buf][2 kk][256 rows][32 k] bf16 per operand = 64 KiB each
  __shared__ unsigned short Alds[32768];
  __shared__ unsigned short Blds[32768];

  const int bid = blockIdx.x;
  const int swz = (bid & 7) * 96 + (bid >> 3);   // bijective: 768 % 8 == 0
  const int mt  = swz / 6;
  const int nt  = swz % 6;
  const int brow = mt * 256;

  const unsigned short* wbase; const float* biasptr;
  int segcol; size_t obase; int hg;
  if (nt < 4)       { wbase = wqb + (size_t)nt * 256 * HIDDEN;  biasptr = bq; segcol = nt * 256; obase = 0u;        hg = 16; }
  else if (nt == 4) { wbase = wqb + (size_t)1024 * HIDDEN;      biasptr = bk; segcol = 0;        obase = 33554432u; hg = 4;  }
  else              { wbase = wqb + (size_t)1280 * HIDDEN;      biasptr = bv; segcol = 0;        obase = 41943040u; hg = 4;  }

  const int t = threadIdx.x;
  const int w = t >> 6, lane = t & 63;
  const int wm = w >> 2, wn = w & 3;
  const int l15 = lane & 15, hi = lane >> 4;

  // staging: rows 32w..32w+31; lane row = 32w + (lane>>2), granule (lane&3)^((row>>1)&3)
  const int sr  = 2 * w * 16 + (lane >> 2);
  const int scg = ((lane & 3) ^ ((lane >> 3) & 3)) * 8;
  const unsigned short* aST = xn    + (size_t)(brow + sr) * HIDDEN + scg;
  const unsigned short* bST = wbase + (size_t)sr * HIDDEN + scg;
  const int ldsq = 2 * w * 512;   // wave-uniform; HW adds lane*16B

  // ds_read: addr = buf*16384 + kk*8192 + row*32 + (hi ^ ((row>>1)&3))*8
  const int rdx  = (hi ^ ((l15 >> 1) & 3)) * 8;
  const int rowA = wm * 128 + l15;
  const int rowB = wn * 64  + l15;

  f32x4 acc[8][4];
#pragma unroll
  for (int m = 0; m < 8; ++m)
#pragma unroll
    for (int n = 0; n < 4; ++n) acc[m][n] = (f32x4){0.f, 0.f, 0.f, 0.f};
  bf16x8 a0[4], a1[4], b0[4], b1[4];

#define STA(BUF, KK, KT) do {                                                   \
    unsigned short* _d = Alds + (BUF) * 16384 + (KK) * 8192 + ldsq;             \
    const unsigned short* _s = aST + (size_t)((KT) * 64 + (KK) * 32);           \
    __builtin_amdgcn_global_load_lds(GLOBAL_AS(_s), LDS_AS(_d), 16, 0, 0);      \
    __builtin_amdgcn_global_load_lds(GLOBAL_AS(_s + 16 * HIDDEN), LDS_AS(_d + 512), 16, 0, 0); \
  } while (0)
#define STB(BUF, KK, KT) do {                                                   \
    unsigned short* _d = Blds + (BUF) * 16384 + (KK) * 8192 + ldsq;             \
    const unsigned short* _s = bST + (size_t)((KT) * 64 + (KK) * 32);           \
    __builtin_amdgcn_global_load_lds(GLOBAL_AS(_s), LDS_AS(_d), 16, 0, 0);      \
    __builtin_amdgcn_global_load_lds(GLOBAL_AS(_s + 16 * HIDDEN), LDS_AS(_d + 512), 16, 0, 0); \
  } while (0)
#define RDA(SET, BUF, KK, MH) do { _Pragma("unroll")                            \
    for (int m = 0; m < 4; ++m)                                                 \
      SET[m] = *(const bf16x8*)(Alds + (BUF) * 16384 + (KK) * 8192 + (rowA + (MH) * 64 + m * 16) * 32 + rdx); \
  } while (0)
#define RDB(SET, BUF, KK) do { _Pragma("unroll")                                \
    for (int n = 0; n < 4; ++n)                                                 \
      SET[n] = *(const bf16x8*)(Blds + (BUF) * 16384 + (KK) * 8192 + (rowB + n * 16) * 32 + rdx); \
  } while (0)
#define MMX(ASET, BSET, MH) do {                                                \
    __builtin_amdgcn_s_setprio(1);                                              \
    _Pragma("unroll") for (int m = 0; m < 4; ++m)                               \
      _Pragma("unroll") for (int n = 0; n < 4; ++n)                             \
        acc[(MH) * 4 + m][n] = __builtin_amdgcn_mfma_f32_16x16x32_bf16(ASET[m], BSET[n], acc[(MH) * 4 + m][n], 0, 0, 0); \
    __builtin_amdgcn_s_setprio(0);                                              \
  } while (0)
#define ENDPH(VMN) do {                                                         \
    asm volatile("s_waitcnt lgkmcnt(0)" ::: "memory");                          \
    asm volatile("s_waitcnt vmcnt(" #VMN ")" ::: "memory");                     \
    __builtin_amdgcn_sched_barrier(0);                                          \
    __builtin_amdgcn_s_barrier();                                               \
    __builtin_amdgcn_sched_barrier(0);                                          \
  } while (0)

  // prologue: stage tiles 0 (buf0) and 1 (buf1) fully = 8 macros, 16 loads.
  STA(0, 0, 0); STB(0, 0, 0); STA(0, 1, 0); STB(0, 1, 0);
  STA(1, 0, 1); STB(1, 0, 1); STA(1, 1, 1); STB(1, 1, 1);
  asm volatile("s_waitcnt vmcnt(12)" ::: "memory");   // validate A00,B00 (all waves, via barrier)
  __builtin_amdgcn_sched_barrier(0);
  __builtin_amdgcn_s_barrier();
  __builtin_amdgcn_sched_barrier(0);
  RDA(a0, 0, 0, 0); RDB(b0, 0, 0);
  asm volatile("s_waitcnt lgkmcnt(0)" ::: "memory");
  __builtin_amdgcn_sched_barrier(0);
  // RACE FIX (R10->R11): all waves must finish their prologue ds_reads of
  // tile-0 A00/B00 before any wave's P0 STB(B00, tile2) writes can land.
  __builtin_amdgcn_s_barrier();
  __builtin_amdgcn_sched_barrier(0);

  for (int i = 0; i < 7; ++i) {
    const int T = 2 * i;
    /*P0*/ STB(0, 0, T + 2); RDA(a1, 0, 0, 1);                  MMX(a0, b0, 0); ENDPH(10);
    /*P1*/ STA(0, 0, T + 2); RDA(a0, 0, 1, 0); RDB(b1, 0, 1);   MMX(a1, b0, 1); ENDPH(10);
    /*P2*/ STB(0, 1, T + 2); RDA(a1, 0, 1, 1);                  MMX(a0, b1, 0); ENDPH(10);
    /*P3*/ STA(0, 1, T + 2); RDA(a0, 1, 0, 0); RDB(b0, 1, 0);   MMX(a1, b1, 1); ENDPH(10);
    /*P4*/ STB(1, 0, T + 3); RDA(a1, 1, 0, 1);                  MMX(a0, b0, 0); ENDPH(10);
    /*P5*/ STA(1, 0, T + 3); RDA(a0, 1, 1, 0); RDB(b1, 1, 1);   MMX(a1, b0, 1); ENDPH(10);
    /*P6*/ STB(1, 1, T + 3); RDA(a1, 1, 1, 1);                  MMX(a0, b1, 0); ENDPH(10);
    /*P7*/ STA(1, 1, T + 3); RDA(a0, 0, 0, 0); RDB(b0, 0, 0);   MMX(a1, b1, 1); ENDPH(10);
  }
  // tail (iter 7, tiles 14/15 staged by iter 6): no stages; drains 8/6/4/2/0.
  /*P0*/ RDA(a1, 0, 0, 1);                  MMX(a0, b0, 0); ENDPH(8);
  /*P1*/ RDA(a0, 0, 1, 0); RDB(b1, 0, 1);   MMX(a1, b0, 1); ENDPH(6);
  /*P2*/ RDA(a1, 0, 1, 1);                  MMX(a0, b1, 0); ENDPH(4);
  /*P3*/ RDA(a0, 1, 0, 0); RDB(b0, 1, 0);   MMX(a1, b1, 1); ENDPH(2);
  /*P4*/ RDA(a1, 1, 0, 1);                  MMX(a0, b0, 0); ENDPH(0);
  /*P5*/ RDA(a0, 1, 1, 0); RDB(b1, 1, 1);   MMX(a1, b0, 1); ENDPH(0);
  /*P6*/ RDA(a1, 1, 1, 1);                  MMX(a0, b1, 0); ENDPH(0);
  /*P7*/                                    MMX(a1, b1, 1);
  asm volatile("s_waitcnt lgkmcnt(0)" ::: "memory");

#undef STA
#undef STB
#undef RDA
#undef RDB
#undef MMX
#undef ENDPH

  // ---- epilogue: coalesced (R9). Wave output = contiguous [128 tok][64 d]
  // fp32 (one head/group). Per 16-token chunk: acc+bias -> LDS (stride 84,
  // 2-way max) -> float4 reads -> 1KB-contiguous stores. Per-wave-disjoint.
  float* ep = (float*)Alds;               // 8 waves x 16 x 84 f32 = 43008 B
  const int epb = w * 1344;
  const int headcol = segcol + wn * 64;
  const int gidx = headcol >> 6;
  const int tok0 = brow + wm * 128;
  const int b_ = tok0 >> 12;
  float* wout = out + obase + (size_t)(b_ * hg + gidx) * 262144u
                    + (size_t)(tok0 & 4095) * 64u;
  float biasv[4];
#pragma unroll
  for (int n = 0; n < 4; ++n) biasv[n] = biasptr[headcol + n * 16 + l15];

#pragma unroll
  for (int m = 0; m < 8; ++m) {
#pragma unroll
    for (int n = 0; n < 4; ++n)
#pragma unroll
      for (int j = 0; j < 4; ++j)
        ep[epb + (hi * 4 + j) * 84 + n * 16 + l15] = acc[m][n][j] + biasv[n];
    asm volatile("s_waitcnt lgkmcnt(0)" ::: "memory");
#pragma unroll
    for (int it = 0; it < 4; ++it) {
      const int r = it * 4 + hi;
      const float4 v = *(const float4*)(ep + epb + r * 84 + l15 * 4);
      *(float4*)(wout + (size_t)(m * 16 + r) * 64 + l15 * 4) = v;
    }
  }
}

extern "C" void kernel_launch(void* const* d_in, const int* in_sizes, int n_in,
                              void* d_out, int out_size, void* d_ws, size_t ws_size,
                              hipStream_t stream) {
  const float* x  = (const float*)d_in[0];
  const float* wq = (const float*)d_in[1];
  const float* wk = (const float*)d_in[2];
  const float* wv = (const float*)d_in[3];
  const float* bq = (const float*)d_in[4];
  const float* bk = (const float*)d_in[5];
  const float* bv = (const float*)d_in[6];
  const float* g  = (const float*)d_in[7];
  const float* be = (const float*)d_in[8];
  float* out = (float*)d_out;

  unsigned short* xn = (unsigned short*)d_ws;                          // 64 MiB
  unsigned short* wb = (unsigned short*)((char*)d_ws + (64u << 20));   // 3 MiB (wq|wk|wv bf16)

  ln_cvt_kernel<<<NTOK + 1536, 256, 0, stream>>>(x, g, be, wq, wk, wv, xn, wb);
  qkv_gemm<<<768, 512, 0, stream>>>(xn, wb, bq, bk, bv, out);
}

// Round 12
// 169.287 us; speedup vs baseline: 1.2274x; 1.0116x over previous
//
#include <hip/hip_runtime.h>
#include <hip/hip_bf16.h>

// InputProjection: shared LayerNorm + Q/K/V projections (fp32 in, fp32 out).
// R12 = R11 + phase-interior fixes:
//  (a) sched_barrier(0) between {stage, ds_read issue} and the MFMA cluster —
//      pins reads BEFORE MFMAs in the emitted code so the DS pipe drains them
//      under the MFMA cluster (previously the scheduler could sink them after,
//      serializing DS+MFMA -> the measured 34% MfmaUtil).
//  (b) setprio removed: with reads and MFMA co-issued in the same window and
//      2 waves/SIMD, prio-1 MFMA starves the other wave's prio-0 read issue
//      (T5's regime gate — it helps the 2-region m201 phase, not this one).

#define HIDDEN 1024
#define NTOK   32768

typedef __bf16 bf16x8 __attribute__((ext_vector_type(8)));
typedef float  f32x4  __attribute__((ext_vector_type(4)));

#define GLOBAL_AS(p) ((const __attribute__((address_space(1))) void*)(p))
#define LDS_AS(p)    ((__attribute__((address_space(3))) void*)(p))

__device__ __forceinline__ unsigned short f2bf(float f) {
  union { float f; unsigned int i; } x; x.f = f;
  unsigned int r = x.i + 0x7FFFu + ((x.i >> 16) & 1u);   // RNE
  return (unsigned short)(r >> 16);
}

// ---------------- K1: LayerNorm (fp32 in, bf16 out) + weight cvt ----------------
__global__ __launch_bounds__(256) void ln_cvt_kernel(
    const float* __restrict__ x,
    const float* __restrict__ gamma,
    const float* __restrict__ beta,
    const float* __restrict__ wq,
    const float* __restrict__ wk,
    const float* __restrict__ wv,
    unsigned short* __restrict__ xn,
    unsigned short* __restrict__ wb) {
  const int bid = blockIdx.x;
  const int t   = threadIdx.x;
  if (bid < NTOK) {
    const size_t base = (size_t)bid * HIDDEN;
    const float4 v = ((const float4*)(x + base))[t];
    float s  = v.x + v.y + v.z + v.w;
    float s2 = v.x*v.x + v.y*v.y + v.z*v.z + v.w*v.w;
#pragma unroll
    for (int off = 32; off >= 1; off >>= 1) {
      s  += __shfl_xor(s,  off);
      s2 += __shfl_xor(s2, off);
    }
    __shared__ float red[8];
    const int w = t >> 6;
    if ((t & 63) == 0) { red[w] = s; red[4 + w] = s2; }
    __syncthreads();
    s  = red[0] + red[1] + red[2] + red[3];
    s2 = red[4] + red[5] + red[6] + red[7];
    const float mu   = s * (1.0f / HIDDEN);
    const float rstd = rsqrtf(s2 * (1.0f / HIDDEN) - mu * mu + 1e-5f);
    const float4 g  = ((const float4*)gamma)[t];
    const float4 bb = ((const float4*)beta)[t];
    ushort4 o;
    o.x = f2bf((v.x - mu) * rstd * g.x + bb.x);
    o.y = f2bf((v.y - mu) * rstd * g.y + bb.y);
    o.z = f2bf((v.z - mu) * rstd * g.z + bb.z);
    o.w = f2bf((v.w - mu) * rstd * g.w + bb.w);
    ((ushort4*)(xn + base))[t] = o;
  } else {
    const int b2 = bid - NTOK;           // 0..1535; 1024 wq, 256 wk, 256 wv
    const float* src;
    int off;
    if (b2 < 1024)      { src = wq; off = b2; }
    else if (b2 < 1280) { src = wk; off = b2 - 1024; }
    else                { src = wv; off = b2 - 1280; }
    const float4 v = ((const float4*)src)[off * 256 + t];
    ushort4 o;
    o.x = f2bf(v.x); o.y = f2bf(v.y); o.z = f2bf(v.z); o.w = f2bf(v.w);
    ((ushort4*)wb)[b2 * 256 + t] = o;
  }
}

// ---------------- K2: 8-phase pipelined QKV GEMM ----------------
// 768 blocks (128 M x 6 N), 512 threads (8 waves, 2M x 4N), wave tile 128x64.
__global__ __launch_bounds__(512, 2) void qkv_gemm(
    const unsigned short* __restrict__ xn,
    const unsigned short* __restrict__ wqb,
    const float* __restrict__ bq,
    const float* __restrict__ bk,
    const float* __restrict__ bv,
    float* __restrict__ out) {
  // [2 buf][2 kk][256 rows][32 k] bf16 per operand = 64 KiB each
  __shared__ unsigned short Alds[32768];
  __shared__ unsigned short Blds[32768];

  const int bid = blockIdx.x;
  const int swz = (bid & 7) * 96 + (bid >> 3);   // bijective: 768 % 8 == 0
  const int mt  = swz / 6;
  const int nt  = swz % 6;
  const int brow = mt * 256;

  const unsigned short* wbase; const float* biasptr;
  int segcol; size_t obase; int hg;
  if (nt < 4)       { wbase = wqb + (size_t)nt * 256 * HIDDEN;  biasptr = bq; segcol = nt * 256; obase = 0u;        hg = 16; }
  else if (nt == 4) { wbase = wqb + (size_t)1024 * HIDDEN;      biasptr = bk; segcol = 0;        obase = 33554432u; hg = 4;  }
  else              { wbase = wqb + (size_t)1280 * HIDDEN;      biasptr = bv; segcol = 0;        obase = 41943040u; hg = 4;  }

  const int t = threadIdx.x;
  const int w = t >> 6, lane = t & 63;
  const int wm = w >> 2, wn = w & 3;
  const int l15 = lane & 15, hi = lane >> 4;

  // staging: rows 32w..32w+31; lane row = 32w + (lane>>2), granule (lane&3)^((row>>1)&3)
  const int sr  = 2 * w * 16 + (lane >> 2);
  const int scg = ((lane & 3) ^ ((lane >> 3) & 3)) * 8;
  const unsigned short* aST = xn    + (size_t)(brow + sr) * HIDDEN + scg;
  const unsigned short* bST = wbase + (size_t)sr * HIDDEN + scg;
  const int ldsq = 2 * w * 512;   // wave-uniform; HW adds lane*16B

  // ds_read: addr = buf*16384 + kk*8192 + row*32 + (hi ^ ((row>>1)&3))*8
  const int rdx  = (hi ^ ((l15 >> 1) & 3)) * 8;
  const int rowA = wm * 128 + l15;
  const int rowB = wn * 64  + l15;

  f32x4 acc[8][4];
#pragma unroll
  for (int m = 0; m < 8; ++m)
#pragma unroll
    for (int n = 0; n < 4; ++n) acc[m][n] = (f32x4){0.f, 0.f, 0.f, 0.f};
  bf16x8 a0[4], a1[4], b0[4], b1[4];

#define STA(BUF, KK, KT) do {                                                   \
    unsigned short* _d = Alds + (BUF) * 16384 + (KK) * 8192 + ldsq;             \
    const unsigned short* _s = aST + (size_t)((KT) * 64 + (KK) * 32);           \
    __builtin_amdgcn_global_load_lds(GLOBAL_AS(_s), LDS_AS(_d), 16, 0, 0);      \
    __builtin_amdgcn_global_load_lds(GLOBAL_AS(_s + 16 * HIDDEN), LDS_AS(_d + 512), 16, 0, 0); \
  } while (0)
#define STB(BUF, KK, KT) do {                                                   \
    unsigned short* _d = Blds + (BUF) * 16384 + (KK) * 8192 + ldsq;             \
    const unsigned short* _s = bST + (size_t)((KT) * 64 + (KK) * 32);           \
    __builtin_amdgcn_global_load_lds(GLOBAL_AS(_s), LDS_AS(_d), 16, 0, 0);      \
    __builtin_amdgcn_global_load_lds(GLOBAL_AS(_s + 16 * HIDDEN), LDS_AS(_d + 512), 16, 0, 0); \
  } while (0)
#define RDA(SET, BUF, KK, MH) do { _Pragma("unroll")                            \
    for (int m = 0; m < 4; ++m)                                                 \
      SET[m] = *(const bf16x8*)(Alds + (BUF) * 16384 + (KK) * 8192 + (rowA + (MH) * 64 + m * 16) * 32 + rdx); \
  } while (0)
#define RDB(SET, BUF, KK) do { _Pragma("unroll")                                \
    for (int n = 0; n < 4; ++n)                                                 \
      SET[n] = *(const bf16x8*)(Blds + (BUF) * 16384 + (KK) * 8192 + (rowB + n * 16) * 32 + rdx); \
  } while (0)
// PIN: pin {stage, ds_read} issue BEFORE the MFMA cluster (rule #18 family)
#define PIN __builtin_amdgcn_sched_barrier(0)
#define MMX(ASET, BSET, MH) do {                                                \
    _Pragma("unroll") for (int m = 0; m < 4; ++m)                               \
      _Pragma("unroll") for (int n = 0; n < 4; ++n)                             \
        acc[(MH) * 4 + m][n] = __builtin_amdgcn_mfma_f32_16x16x32_bf16(ASET[m], BSET[n], acc[(MH) * 4 + m][n], 0, 0, 0); \
  } while (0)
#define ENDPH(VMN) do {                                                         \
    asm volatile("s_waitcnt lgkmcnt(0)" ::: "memory");                          \
    asm volatile("s_waitcnt vmcnt(" #VMN ")" ::: "memory");                     \
    __builtin_amdgcn_sched_barrier(0);                                          \
    __builtin_amdgcn_s_barrier();                                               \
    __builtin_amdgcn_sched_barrier(0);                                          \
  } while (0)

  // prologue: stage tiles 0 (buf0) and 1 (buf1) fully = 8 macros, 16 loads.
  STA(0, 0, 0); STB(0, 0, 0); STA(0, 1, 0); STB(0, 1, 0);
  STA(1, 0, 1); STB(1, 0, 1); STA(1, 1, 1); STB(1, 1, 1);
  asm volatile("s_waitcnt vmcnt(12)" ::: "memory");   // validate A00,B00
  __builtin_amdgcn_sched_barrier(0);
  __builtin_amdgcn_s_barrier();
  __builtin_amdgcn_sched_barrier(0);
  RDA(a0, 0, 0, 0); RDB(b0, 0, 0);
  asm volatile("s_waitcnt lgkmcnt(0)" ::: "memory");
  __builtin_amdgcn_sched_barrier(0);
  // prologue race fix (R11): all waves drain tile-0 reads before loop stages.
  __builtin_amdgcn_s_barrier();
  __builtin_amdgcn_sched_barrier(0);

  for (int i = 0; i < 7; ++i) {
    const int T = 2 * i;
    /*P0*/ STB(0, 0, T + 2); RDA(a1, 0, 0, 1);                PIN; MMX(a0, b0, 0); ENDPH(10);
    /*P1*/ STA(0, 0, T + 2); RDA(a0, 0, 1, 0); RDB(b1, 0, 1); PIN; MMX(a1, b0, 1); ENDPH(10);
    /*P2*/ STB(0, 1, T + 2); RDA(a1, 0, 1, 1);                PIN; MMX(a0, b1, 0); ENDPH(10);
    /*P3*/ STA(0, 1, T + 2); RDA(a0, 1, 0, 0); RDB(b0, 1, 0); PIN; MMX(a1, b1, 1); ENDPH(10);
    /*P4*/ STB(1, 0, T + 3); RDA(a1, 1, 0, 1);                PIN; MMX(a0, b0, 0); ENDPH(10);
    /*P5*/ STA(1, 0, T + 3); RDA(a0, 1, 1, 0); RDB(b1, 1, 1); PIN; MMX(a1, b0, 1); ENDPH(10);
    /*P6*/ STB(1, 1, T + 3); RDA(a1, 1, 1, 1);                PIN; MMX(a0, b1, 0); ENDPH(10);
    /*P7*/ STA(1, 1, T + 3); RDA(a0, 0, 0, 0); RDB(b0, 0, 0); PIN; MMX(a1, b1, 1); ENDPH(10);
  }
  // tail (iter 7, tiles 14/15 staged by iter 6): no stages; drains 8/6/4/2/0.
  /*P0*/ RDA(a1, 0, 0, 1);                PIN; MMX(a0, b0, 0); ENDPH(8);
  /*P1*/ RDA(a0, 0, 1, 0); RDB(b1, 0, 1); PIN; MMX(a1, b0, 1); ENDPH(6);
  /*P2*/ RDA(a1, 0, 1, 1);                PIN; MMX(a0, b1, 0); ENDPH(4);
  /*P3*/ RDA(a0, 1, 0, 0); RDB(b0, 1, 0); PIN; MMX(a1, b1, 1); ENDPH(2);
  /*P4*/ RDA(a1, 1, 0, 1);                PIN; MMX(a0, b0, 0); ENDPH(0);
  /*P5*/ RDA(a0, 1, 1, 0); RDB(b1, 1, 1); PIN; MMX(a1, b0, 1); ENDPH(0);
  /*P6*/ RDA(a1, 1, 1, 1);                PIN; MMX(a0, b1, 0); ENDPH(0);
  /*P7*/                                       MMX(a1, b1, 1);
  asm volatile("s_waitcnt lgkmcnt(0)" ::: "memory");

#undef STA
#undef STB
#undef RDA
#undef RDB
#undef MMX
#undef PIN
#undef ENDPH

  // ---- epilogue: coalesced (R9). Wave output = contiguous [128 tok][64 d]
  // fp32 (one head/group). Per 16-token chunk: acc+bias -> LDS (stride 84,
  // 2-way max) -> float4 reads -> 1KB-contiguous stores. Per-wave-disjoint.
  float* ep = (float*)Alds;               // 8 waves x 16 x 84 f32 = 43008 B
  const int epb = w * 1344;
  const int headcol = segcol + wn * 64;
  const int gidx = headcol >> 6;
  const int tok0 = brow + wm * 128;
  const int b_ = tok0 >> 12;
  float* wout = out + obase + (size_t)(b_ * hg + gidx) * 262144u
                    + (size_t)(tok0 & 4095) * 64u;
  float biasv[4];
#pragma unroll
  for (int n = 0; n < 4; ++n) biasv[n] = biasptr[headcol + n * 16 + l15];

#pragma unroll
  for (int m = 0; m < 8; ++m) {
#pragma unroll
    for (int n = 0; n < 4; ++n)
#pragma unroll
      for (int j = 0; j < 4; ++j)
        ep[epb + (hi * 4 + j) * 84 + n * 16 + l15] = acc[m][n][j] + biasv[n];
    asm volatile("s_waitcnt lgkmcnt(0)" ::: "memory");
#pragma unroll
    for (int it = 0; it < 4; ++it) {
      const int r = it * 4 + hi;
      const float4 v = *(const float4*)(ep + epb + r * 84 + l15 * 4);
      *(float4*)(wout + (size_t)(m * 16 + r) * 64 + l15 * 4) = v;
    }
  }
}

extern "C" void kernel_launch(void* const* d_in, const int* in_sizes, int n_in,
                              void* d_out, int out_size, void* d_ws, size_t ws_size,
                              hipStream_t stream) {
  const float* x  = (const float*)d_in[0];
  const float* wq = (const float*)d_in[1];
  const float* wk = (const float*)d_in[2];
  const float* wv = (const float*)d_in[3];
  const float* bq = (const float*)d_in[4];
  const float* bk = (const float*)d_in[5];
  const float* bv = (const float*)d_in[6];
  const float* g  = (const float*)d_in[7];
  const float* be = (const float*)d_in[8];
  float* out = (float*)d_out;

  unsigned short* xn = (unsigned short*)d_ws;                          // 64 MiB
  unsigned short* wb = (unsigned short*)((char*)d_ws + (64u << 20));   // 3 MiB (wq|wk|wv bf16)

  ln_cvt_kernel<<<NTOK + 1536, 256, 0, stream>>>(x, g, be, wq, wk, wv, xn, wb);
  qkv_gemm<<<768, 512, 0, stream>>>(xn, wb, bq, bk, bv, out);
}